// Round 1
// baseline (181.920 us; speedup 1.0000x reference)
//
#include <hip/hip_runtime.h>
#include <stdint.h>

typedef __bf16 bf16_t;
typedef __bf16 bf16x4 __attribute__((ext_vector_type(4)));
typedef __bf16 bf16x8 __attribute__((ext_vector_type(8)));
typedef float  f32x4  __attribute__((ext_vector_type(4)));
typedef float  f32x16 __attribute__((ext_vector_type(16)));

#define D_MODEL 1024
#define SEQ     2048
#define BATCH   2
#define NHEAD   16
#define DHEAD   64
#define NROWS   (BATCH*SEQ)   // 4096
#define LDT     72            // GEMM V-transpose buffer stride (16B-aligned)

// log2(e): folded into Q scale so attn uses v_exp_f32 (exp2) directly.
#define QSCALE  (0.125f * 1.4426950408889634f)

// async 16B global->LDS DMA (m97). LDS dest must be wave-uniform base + lane*16.
__device__ __forceinline__ void async_ld16(const bf16_t* g, bf16_t* l) {
    __builtin_amdgcn_global_load_lds(
        (const __attribute__((address_space(1))) uint32_t*)(uintptr_t)g,
        (__attribute__((address_space(3))) uint32_t*)(uintptr_t)l,
        16, 0, 0);
}

__device__ __forceinline__ bf16x8 cvt8(f32x4 lo, f32x4 hi) {
    bf16x8 o;
#pragma unroll
    for (int i = 0; i < 4; ++i) { o[i] = (bf16_t)lo[i]; o[4 + i] = (bf16_t)hi[i]; }
    return o;
}

__device__ __forceinline__ bf16x4 shflx32(bf16x4 v) {
    union { bf16x4 b; long long u; } x;
    x.b = v;
    x.u = __shfl_xor(x.u, 32);
    return x.b;
}

// ---------------------------------------------------------------------------
// f32 -> bf16 pre-convert of Wq,Wk,Wv,Wo (512 blocks each) + x (2048 blocks).
// ---------------------------------------------------------------------------
__global__ void __launch_bounds__(256)
k_cvt(const float* __restrict__ w0, const float* __restrict__ w1,
      const float* __restrict__ w2, const float* __restrict__ w3,
      const float* __restrict__ x,
      bf16_t* __restrict__ o0, bf16_t* __restrict__ o1,
      bf16_t* __restrict__ o2, bf16_t* __restrict__ o3,
      bf16_t* __restrict__ ox)
{
    const int blk = blockIdx.x;
    const float* s; bf16_t* d; int bi;
    if (blk < 2048) { s = x; d = ox; bi = blk; }
    else {
        const int t = blk - 2048, sel = t >> 9; bi = t & 511;
        s = (sel == 0) ? w0 : (sel == 1) ? w1 : (sel == 2) ? w2 : w3;
        d = (sel == 0) ? o0 : (sel == 1) ? o1 : (sel == 2) ? o2 : o3;
    }
    const size_t i = ((size_t)bi * 256 + threadIdx.x) * 8;
    *(bf16x8*)(d + i) = cvt8(*(const f32x4*)(s + i), *(const f32x4*)(s + i + 4));
}

// ---------------------------------------------------------------------------
// 128x128 GEMM tile: Y = X @ W^T * oscale. A and B bf16. (round-8 structure)
// Staging: global_load_lds width=16, 32-elem LDS rows, XOR-4 chunk swizzle.
// OUT_MODE: 0 = bf16 row-major; 1 = bf16 V^T [bh][dh][s]; 2 = f32 row-major.
// ---------------------------------------------------------------------------
template <int OUT_MODE>
__device__ __forceinline__ void gemm128(bf16_t* __restrict__ smem,
                                        const bf16_t* __restrict__ X,
                                        const bf16_t* __restrict__ W,
                                        void* __restrict__ Yv,
                                        int m0, int n0, float oscale)
{
    bf16_t* lA = smem;                 // 128 x 32
    bf16_t* lB = smem + 128 * 32;      // 128 x 32

    const int tid  = threadIdx.x;
    const int lane = tid & 63;
    const int w    = tid >> 6;
    const int l15  = lane & 15;
    const int quad = lane >> 4;

    const int c0 = tid, c1 = tid + 256;
    const int r0 = c0 >> 2, r1 = c1 >> 2;
    const int kc0 = (c0 & 3) ^ ((r0 >> 1) & 3);
    const int kc1 = (c1 & 3) ^ ((r1 >> 1) & 3);
    const bf16_t* gA0 = X + (size_t)(m0 + r0) * D_MODEL + kc0 * 8;
    const bf16_t* gA1 = X + (size_t)(m0 + r1) * D_MODEL + kc1 * 8;
    const bf16_t* gB0 = W + (size_t)(n0 + r0) * D_MODEL + kc0 * 8;
    const bf16_t* gB1 = W + (size_t)(n0 + r1) * D_MODEL + kc1 * 8;

    int am[4], bn[4];
    const int mw = (w >> 1) * 64, nw = (w & 1) * 64;
#pragma unroll
    for (int i = 0; i < 4; ++i) {
        const int ra = mw + i * 16 + l15;
        am[i] = ra * 32 + (quad ^ ((ra >> 1) & 3)) * 8;
        const int rb = nw + i * 16 + l15;
        bn[i] = rb * 32 + (quad ^ ((rb >> 1) & 3)) * 8;
    }

    f32x4 acc[4][4];
#pragma unroll
    for (int i = 0; i < 4; ++i)
#pragma unroll
        for (int j = 0; j < 4; ++j) acc[i][j] = f32x4{0.f, 0.f, 0.f, 0.f};

    for (int k0 = 0; k0 < D_MODEL; k0 += 32) {
        __syncthreads();
        async_ld16(gA0 + k0, &lA[c0 * 8]);
        async_ld16(gA1 + k0, &lA[c1 * 8]);
        async_ld16(gB0 + k0, &lB[c0 * 8]);
        async_ld16(gB1 + k0, &lB[c1 * 8]);
        __syncthreads();

        bf16x8 af[4], bfr[4];
#pragma unroll
        for (int i = 0; i < 4; ++i) af[i]  = *(const bf16x8*)&lA[am[i]];
#pragma unroll
        for (int i = 0; i < 4; ++i) bfr[i] = *(const bf16x8*)&lB[bn[i]];
#pragma unroll
        for (int mi = 0; mi < 4; ++mi)
#pragma unroll
            for (int ni = 0; ni < 4; ++ni)
                acc[mi][ni] = __builtin_amdgcn_mfma_f32_16x16x32_bf16(
                    af[mi], bfr[ni], acc[mi][ni], 0, 0, 0);
    }

    if constexpr (OUT_MODE == 1) {
        bf16_t* lT = smem;                        // 128 cols x LDT
#pragma unroll
        for (int h0 = 0; h0 < 2; ++h0) {
            __syncthreads();
            if ((w >> 1) == h0) {
#pragma unroll
                for (int mi = 0; mi < 4; ++mi)
#pragma unroll
                    for (int ni = 0; ni < 4; ++ni) {
                        bf16x4 pk;
#pragma unroll
                        for (int r = 0; r < 4; ++r)
                            pk[r] = (bf16_t)(acc[mi][ni][r] * oscale);
                        const int col = nw + ni * 16 + l15;
                        *(bf16x4*)&lT[col * LDT + mi * 16 + quad * 4] = pk;
                    }
            }
            __syncthreads();
            const int col = tid & 127;
            const int seg = tid >> 7;
            const int brow = m0 + h0 * 64;
            const int b = brow >> 11, sb = brow & 2047;
            const int cg = n0 + col;              // h*64+dh
            bf16_t* dst = (bf16_t*)Yv +
                ((size_t)((b << 4) | (cg >> 6)) * 64 + (cg & 63)) * SEQ + sb;
#pragma unroll
            for (int u = 0; u < 4; ++u)
                *(bf16x8*)(dst + seg * 32 + u * 8) =
                    *(const bf16x8*)&lT[col * LDT + seg * 32 + u * 8];
        }
    } else {
        // C/D layout col = lane&15, row = quad*4 + reg (m89-verified)
#pragma unroll
        for (int mi = 0; mi < 4; ++mi)
#pragma unroll
            for (int ni = 0; ni < 4; ++ni)
#pragma unroll
                for (int r = 0; r < 4; ++r) {
                    const int row = m0 + mw + mi * 16 + quad * 4 + r;
                    const int col = n0 + nw + ni * 16 + l15;
                    const float vv = acc[mi][ni][r] * oscale;
                    if constexpr (OUT_MODE == 0)
                        ((bf16_t*)Yv)[(size_t)row * D_MODEL + col] = (bf16_t)vv;
                    else
                        ((float*)Yv)[(size_t)row * D_MODEL + col] = vv;
                }
    }
}

__global__ void __launch_bounds__(256, 3)
k_gemm_qkv(const bf16_t* __restrict__ X,
           const bf16_t* __restrict__ Wq, const bf16_t* __restrict__ Wk,
           const bf16_t* __restrict__ Wv,
           bf16_t* __restrict__ Qb, bf16_t* __restrict__ Kb, bf16_t* __restrict__ Vt)
{
    __shared__ __align__(16) bf16_t smem[128 * LDT];   // 18432 B
    const int sel = blockIdx.y >> 3;           // 0=Q 1=K 2=V
    const int n0  = (blockIdx.y & 7) * 128;
    const int m0  = blockIdx.x * 128;
    if (sel == 0)      gemm128<0>(smem, X, Wq, Qb, m0, n0, QSCALE);
    else if (sel == 1) gemm128<0>(smem, X, Wk, Kb, m0, n0, 1.0f);
    else               gemm128<1>(smem, X, Wv, Vt, m0, n0, 1.0f);
}

__global__ void __launch_bounds__(256, 3)
k_gemm_out(const bf16_t* __restrict__ X, const bf16_t* __restrict__ W,
           float* __restrict__ Y)
{
    __shared__ __align__(16) bf16_t smem[128 * LDT];
    gemm128<2>(smem, X, W, Y, blockIdx.x * 128, blockIdx.y * 128, 1.0f);
}

// ---------------------------------------------------------------------------
// Attention, Q-tile 128, in-register P. 4 waves, wave w owns q-strip w*32..+31.
// This round (T3 minimum 2-phase): double-buffered K/V LDS, stage tile t+1 is
// issued BEFORE computing tile t; ONE raw barrier per tile with per-wave
// vmcnt(0) fused into the same asm (memory clobber orders the LDS reads).
// Invariant: at the barrier every wave's DMA into buf^1 has landed (own
// vmcnt(0) precedes it) and every wave's ds_reads of buf are already consumed
// by its MFMAs, so re-staging buf next iteration cannot race a reader.
// VALU diet: exp2 with log2(e) folded into Q projection (QSCALE); row-sum via
// ones-column MFMA into acc_s whose 32x32 C-layout matches acc_o row-for-row,
// so the epilogue divide is register-local (no sbuf / shuffle / barrier).
// Ob may alias Qb (Q read to regs up-front; block-disjoint slices).
// ---------------------------------------------------------------------------
__global__ void __launch_bounds__(256, 2)
k_attn(const bf16_t* __restrict__ Qb, const bf16_t* __restrict__ Kb,
       const bf16_t* __restrict__ Vt, bf16_t* __restrict__ Ob)
{
    __shared__ __align__(16) bf16_t lK[2][64 * 64];   // [buf][kv][dh], swizzled
    __shared__ __align__(16) bf16_t lV[2][64 * 64];   // [buf][dh][kv], swizzled

    const int tid  = threadIdx.x;
    const int lane = tid & 63;
    const int w    = tid >> 6;    // q-strip
    const int l31  = lane & 31;
    const int h    = lane >> 5;

    const int bh = blockIdx.x;    // 0..31
    const int b_ = bh >> 4, hh = bh & 15;
    const int q0 = blockIdx.y * 128;

    const size_t base = (size_t)b_ * SEQ * D_MODEL + (size_t)hh * DHEAD;
    const bf16_t* Qp = Qb + base;
    const bf16_t* Kp = Kb + base;
    const bf16_t* Vp = Vt + (size_t)bh * DHEAD * SEQ;   // [dh][s]

    // Q B-frags in regs for the whole kernel (B[n=q=l31][k=c*16+h*8+j])
    const int qrow = q0 + w * 32 + l31;
    bf16x8 qf[4];
#pragma unroll
    for (int c = 0; c < 4; ++c)
        qf[c] = *(const bf16x8*)&Qp[(size_t)qrow * D_MODEL + c * 16 + h * 8];

    // staging: 512 chunks per tile, 2 per thread per tile; chunk c -> row c>>3,
    // slot c&7, global chunk g = (c&7) ^ ((c>>3)&7). Note (r0+32)&7 == r0&7.
    const int c0 = tid, c1 = tid + 256;
    const int r0 = c0 >> 3, g0 = (c0 & 7) ^ (r0 & 7);
    const int r1 = r0 + 32;
    const bf16_t* gK0 = Kp + (size_t)r0 * D_MODEL + g0 * 8;
    const bf16_t* gK1 = Kp + (size_t)r1 * D_MODEL + g0 * 8;
    const bf16_t* gV0 = Vp + (size_t)r0 * SEQ + g0 * 8;
    const bf16_t* gV1 = Vp + (size_t)r1 * SEQ + g0 * 8;

    // fragment read offsets (row-dependent XOR slot)
    int koff[2][4];
#pragma unroll
    for (int half = 0; half < 2; ++half)
#pragma unroll
        for (int c = 0; c < 4; ++c) {
            const int row = half * 32 + l31;           // kv row / dh row
            koff[half][c] = row * 64 + ((2 * c + h) ^ (row & 7)) * 8;
        }

    bf16x8 onef;
#pragma unroll
    for (int i = 0; i < 8; ++i) onef[i] = (bf16_t)1.0f;

    f32x16 acc_o[2];
    f32x16 acc_s;                  // row-sum accumulator (ones-column PV)
#pragma unroll
    for (int i = 0; i < 16; ++i) { acc_o[0][i] = 0.f; acc_o[1][i] = 0.f; acc_s[i] = 0.f; }

    // ---- prologue: stage tile 0 into buf 0, drain, barrier
    async_ld16(gK0, &lK[0][c0 * 8]);
    async_ld16(gK1, &lK[0][c1 * 8]);
    async_ld16(gV0, &lV[0][c0 * 8]);
    async_ld16(gV1, &lV[0][c1 * 8]);
    asm volatile("s_waitcnt vmcnt(0)\n\ts_barrier" ::: "memory");

    int cur = 0;
    const int NT = SEQ / 64;       // 32
    for (int t = 0; t < NT; ++t) {
        // ---- issue next-tile DMA first; latency hides under this tile's math
        if (t + 1 < NT) {
            const int kv0 = (t + 1) * 64;
            async_ld16(gK0 + (size_t)kv0 * D_MODEL, &lK[cur ^ 1][c0 * 8]);
            async_ld16(gK1 + (size_t)kv0 * D_MODEL, &lK[cur ^ 1][c1 * 8]);
            async_ld16(gV0 + kv0, &lV[cur ^ 1][c0 * 8]);
            async_ld16(gV1 + kv0, &lV[cur ^ 1][c1 * 8]);
        }
        const bf16_t* lKc = lK[cur];
        const bf16_t* lVc = lV[cur];

        // ---- S^T (both kv halves) + exp2 + pack into registers
        bf16x4 pk[2][4];                 // [half][g], lane's h' = h quarter
#pragma unroll
        for (int half = 0; half < 2; ++half) {
            f32x16 st;
#pragma unroll
            for (int i = 0; i < 16; ++i) st[i] = 0.f;
            __builtin_amdgcn_s_setprio(1);
#pragma unroll
            for (int c = 0; c < 4; ++c) {
                bf16x8 kf = *(const bf16x8*)&lKc[koff[half][c]];
                st = __builtin_amdgcn_mfma_f32_32x32x16_bf16(kf, qf[c], st, 0, 0, 0);
            }
            __builtin_amdgcn_s_setprio(0);
#pragma unroll
            for (int g = 0; g < 4; ++g)
#pragma unroll
                for (int r = 0; r < 4; ++r)
                    pk[half][g][r] = (bf16_t)__builtin_amdgcn_exp2f(st[g * 4 + r]);
        }

        // ---- partner exchange: pt[half][g] = partner lane's (h'=1-h) quarter
        bf16x4 pt[2][4];
#pragma unroll
        for (int half = 0; half < 2; ++half)
#pragma unroll
            for (int g = 0; g < 4; ++g) pt[half][g] = shflx32(pk[half][g]);

        // ---- assemble PV A-frags in registers:
        // chunk c needs kv = c*16+h*8+0..7 = {src g=2(c&1)+h, h'=0}++{same g, h'=1}
        bf16x8 pf[4];
#pragma unroll
        for (int c = 0; c < 4; ++c) {
            const int half = c >> 1, e = 2 * (c & 1);
            bf16x4 lo = h ? pt[half][e + 1] : pk[half][e];
            bf16x4 hi = h ? pk[half][e + 1] : pt[half][e];
#pragma unroll
            for (int i = 0; i < 4; ++i) { pf[c][i] = lo[i]; pf[c][4 + i] = hi[i]; }
        }

        // ---- PV + ones-column row-sum: D[m=q][n], A in regs, B from lV / ones
        __builtin_amdgcn_s_setprio(1);
#pragma unroll
        for (int c = 0; c < 4; ++c)
            acc_s = __builtin_amdgcn_mfma_f32_32x32x16_bf16(pf[c], onef, acc_s, 0, 0, 0);
#pragma unroll
        for (int a = 0; a < 2; ++a)
#pragma unroll
            for (int c = 0; c < 4; ++c) {
                bf16x8 vf = *(const bf16x8*)&lVc[koff[a][c]];
                acc_o[a] = __builtin_amdgcn_mfma_f32_32x32x16_bf16(
                    pf[c], vf, acc_o[a], 0, 0, 0);
            }
        __builtin_amdgcn_s_setprio(0);

        // ---- own DMA landed (vmcnt) then block-wide rendezvous; fused in one
        // asm so no LDS access can be scheduled between wait and barrier.
        asm volatile("s_waitcnt vmcnt(0)\n\ts_barrier" ::: "memory");
        cur ^= 1;
    }

    // ---- epilogue: O / rowsum, all register-local (acc_s layout == acc_o)
#pragma unroll
    for (int g = 0; g < 4; ++g)
#pragma unroll
        for (int r = 0; r < 4; ++r) {
            const float inv = 1.0f / acc_s[g * 4 + r];
            const int ql  = w * 32 + r + 8 * g + 4 * h;   // tile-local q
            const size_t rb = (size_t)(b_ * SEQ + q0 + ql) * D_MODEL
                            + hh * DHEAD + l31;
            Ob[rb]      = (bf16_t)(acc_o[0][g * 4 + r] * inv);
            Ob[rb + 32] = (bf16_t)(acc_o[1][g * 4 + r] * inv);
        }
}

// ---------------------------------------------------------------------------
extern "C" void kernel_launch(void* const* d_in, const int* in_sizes, int n_in,
                              void* d_out, int out_size, void* d_ws, size_t ws_size,
                              hipStream_t stream)
{
    const float* x  = (const float*)d_in[0];
    const float* Wq = (const float*)d_in[1];
    const float* Wk = (const float*)d_in[2];
    const float* Wv = (const float*)d_in[3];
    const float* Wo = (const float*)d_in[4];
    float* out = (float*)d_out;

    const size_t wmat = (size_t)D_MODEL * D_MODEL;  // 1M elements
    const size_t mat  = (size_t)NROWS * D_MODEL;    // 4M elements
    bf16_t* Wqb = (bf16_t*)d_ws;
    bf16_t* Wkb = Wqb + wmat;
    bf16_t* Wvb = Wkb + wmat;
    bf16_t* Wob = Wvb + wmat;
    bf16_t* Xb  = Wob + wmat;
    bf16_t* Qb  = Xb + mat;
    bf16_t* Kb  = Qb + mat;
    bf16_t* Vt  = Kb + mat;                          // [bh][dh][s]
    bf16_t* Ab  = Qb;                                // alias (see k_attn)

    dim3 blk(256);
    k_cvt<<<dim3(4096), blk, 0, stream>>>(Wq, Wk, Wv, Wo, x, Wqb, Wkb, Wvb, Wob, Xb);
    k_gemm_qkv<<<dim3(32, 24), blk, 0, stream>>>(Xb, Wqb, Wkb, Wvb, Qb, Kb, Vt);
    k_attn<<<dim3(32, 16), blk, 0, stream>>>(Qb, Kb, Vt, Ab);
    k_gemm_out<<<dim3(32, 8), blk, 0, stream>>>(Ab, Wob, out);
}

// Round 2
// 179.058 us; speedup vs baseline: 1.0160x; 1.0160x over previous
//
#include <hip/hip_runtime.h>
#include <stdint.h>

typedef __bf16 bf16_t;
typedef __bf16 bf16x4 __attribute__((ext_vector_type(4)));
typedef __bf16 bf16x8 __attribute__((ext_vector_type(8)));
typedef float  f32x4  __attribute__((ext_vector_type(4)));
typedef float  f32x16 __attribute__((ext_vector_type(16)));

#define D_MODEL 1024
#define SEQ     2048
#define BATCH   2
#define NHEAD   16
#define DHEAD   64
#define NROWS   (BATCH*SEQ)   // 4096
#define LDT     72            // GEMM V-transpose buffer stride (16B-aligned)

// log2(e): folded into Q scale so attn uses v_exp_f32 (exp2) directly.
#define QSCALE  (0.125f * 1.4426950408889634f)

// async 16B global->LDS DMA (m97). LDS dest must be wave-uniform base + lane*16.
__device__ __forceinline__ void async_ld16(const bf16_t* g, bf16_t* l) {
    __builtin_amdgcn_global_load_lds(
        (const __attribute__((address_space(1))) uint32_t*)(uintptr_t)g,
        (__attribute__((address_space(3))) uint32_t*)(uintptr_t)l,
        16, 0, 0);
}

__device__ __forceinline__ bf16x8 cvt8(f32x4 lo, f32x4 hi) {
    bf16x8 o;
#pragma unroll
    for (int i = 0; i < 4; ++i) { o[i] = (bf16_t)lo[i]; o[4 + i] = (bf16_t)hi[i]; }
    return o;
}

// v_permlane32_swap_b32 a, b:  a' = {a[0:31], b[0:31]},  b' = {a[32:63], b[32:63]}
// (lane-indexed: a'[l<32]=a[l], a'[l>=32]=b[l-32]; b'[l<32]=a[l+32], b'[l>=32]=b[l])
__device__ __forceinline__ void plswap(uint32_t& a, uint32_t& b) {
    asm("v_permlane32_swap_b32 %0, %1" : "+v"(a), "+v"(b));
}

// ---------------------------------------------------------------------------
// f32 -> bf16 pre-convert of Wq,Wk,Wv,Wo (512 blocks each) + x (2048 blocks).
// ---------------------------------------------------------------------------
__global__ void __launch_bounds__(256)
k_cvt(const float* __restrict__ w0, const float* __restrict__ w1,
      const float* __restrict__ w2, const float* __restrict__ w3,
      const float* __restrict__ x,
      bf16_t* __restrict__ o0, bf16_t* __restrict__ o1,
      bf16_t* __restrict__ o2, bf16_t* __restrict__ o3,
      bf16_t* __restrict__ ox)
{
    const int blk = blockIdx.x;
    const float* s; bf16_t* d; int bi;
    if (blk < 2048) { s = x; d = ox; bi = blk; }
    else {
        const int t = blk - 2048, sel = t >> 9; bi = t & 511;
        s = (sel == 0) ? w0 : (sel == 1) ? w1 : (sel == 2) ? w2 : w3;
        d = (sel == 0) ? o0 : (sel == 1) ? o1 : (sel == 2) ? o2 : o3;
    }
    const size_t i = ((size_t)bi * 256 + threadIdx.x) * 8;
    *(bf16x8*)(d + i) = cvt8(*(const f32x4*)(s + i), *(const f32x4*)(s + i + 4));
}

// ---------------------------------------------------------------------------
// 128x128 GEMM tile: Y = X @ W^T * oscale. A and B bf16. (round-8 structure)
// Staging: global_load_lds width=16, 32-elem LDS rows, XOR-4 chunk swizzle.
// OUT_MODE: 0 = bf16 row-major; 1 = bf16 V^T [bh][dh][s]; 2 = f32 row-major.
// ---------------------------------------------------------------------------
template <int OUT_MODE>
__device__ __forceinline__ void gemm128(bf16_t* __restrict__ smem,
                                        const bf16_t* __restrict__ X,
                                        const bf16_t* __restrict__ W,
                                        void* __restrict__ Yv,
                                        int m0, int n0, float oscale)
{
    bf16_t* lA = smem;                 // 128 x 32
    bf16_t* lB = smem + 128 * 32;      // 128 x 32

    const int tid  = threadIdx.x;
    const int lane = tid & 63;
    const int w    = tid >> 6;
    const int l15  = lane & 15;
    const int quad = lane >> 4;

    const int c0 = tid, c1 = tid + 256;
    const int r0 = c0 >> 2, r1 = c1 >> 2;
    const int kc0 = (c0 & 3) ^ ((r0 >> 1) & 3);
    const int kc1 = (c1 & 3) ^ ((r1 >> 1) & 3);
    const bf16_t* gA0 = X + (size_t)(m0 + r0) * D_MODEL + kc0 * 8;
    const bf16_t* gA1 = X + (size_t)(m0 + r1) * D_MODEL + kc1 * 8;
    const bf16_t* gB0 = W + (size_t)(n0 + r0) * D_MODEL + kc0 * 8;
    const bf16_t* gB1 = W + (size_t)(n0 + r1) * D_MODEL + kc1 * 8;

    int am[4], bn[4];
    const int mw = (w >> 1) * 64, nw = (w & 1) * 64;
#pragma unroll
    for (int i = 0; i < 4; ++i) {
        const int ra = mw + i * 16 + l15;
        am[i] = ra * 32 + (quad ^ ((ra >> 1) & 3)) * 8;
        const int rb = nw + i * 16 + l15;
        bn[i] = rb * 32 + (quad ^ ((rb >> 1) & 3)) * 8;
    }

    f32x4 acc[4][4];
#pragma unroll
    for (int i = 0; i < 4; ++i)
#pragma unroll
        for (int j = 0; j < 4; ++j) acc[i][j] = f32x4{0.f, 0.f, 0.f, 0.f};

    for (int k0 = 0; k0 < D_MODEL; k0 += 32) {
        __syncthreads();
        async_ld16(gA0 + k0, &lA[c0 * 8]);
        async_ld16(gA1 + k0, &lA[c1 * 8]);
        async_ld16(gB0 + k0, &lB[c0 * 8]);
        async_ld16(gB1 + k0, &lB[c1 * 8]);
        __syncthreads();

        bf16x8 af[4], bfr[4];
#pragma unroll
        for (int i = 0; i < 4; ++i) af[i]  = *(const bf16x8*)&lA[am[i]];
#pragma unroll
        for (int i = 0; i < 4; ++i) bfr[i] = *(const bf16x8*)&lB[bn[i]];
#pragma unroll
        for (int mi = 0; mi < 4; ++mi)
#pragma unroll
            for (int ni = 0; ni < 4; ++ni)
                acc[mi][ni] = __builtin_amdgcn_mfma_f32_16x16x32_bf16(
                    af[mi], bfr[ni], acc[mi][ni], 0, 0, 0);
    }

    if constexpr (OUT_MODE == 1) {
        bf16_t* lT = smem;                        // 128 cols x LDT
#pragma unroll
        for (int h0 = 0; h0 < 2; ++h0) {
            __syncthreads();
            if ((w >> 1) == h0) {
#pragma unroll
                for (int mi = 0; mi < 4; ++mi)
#pragma unroll
                    for (int ni = 0; ni < 4; ++ni) {
                        bf16x4 pk;
#pragma unroll
                        for (int r = 0; r < 4; ++r)
                            pk[r] = (bf16_t)(acc[mi][ni][r] * oscale);
                        const int col = nw + ni * 16 + l15;
                        *(bf16x4*)&lT[col * LDT + mi * 16 + quad * 4] = pk;
                    }
            }
            __syncthreads();
            const int col = tid & 127;
            const int seg = tid >> 7;
            const int brow = m0 + h0 * 64;
            const int b = brow >> 11, sb = brow & 2047;
            const int cg = n0 + col;              // h*64+dh
            bf16_t* dst = (bf16_t*)Yv +
                ((size_t)((b << 4) | (cg >> 6)) * 64 + (cg & 63)) * SEQ + sb;
#pragma unroll
            for (int u = 0; u < 4; ++u)
                *(bf16x8*)(dst + seg * 32 + u * 8) =
                    *(const bf16x8*)&lT[col * LDT + seg * 32 + u * 8];
        }
    } else {
        // C/D layout col = lane&15, row = quad*4 + reg (m89-verified)
#pragma unroll
        for (int mi = 0; mi < 4; ++mi)
#pragma unroll
            for (int ni = 0; ni < 4; ++ni)
#pragma unroll
                for (int r = 0; r < 4; ++r) {
                    const int row = m0 + mw + mi * 16 + quad * 4 + r;
                    const int col = n0 + nw + ni * 16 + l15;
                    const float vv = acc[mi][ni][r] * oscale;
                    if constexpr (OUT_MODE == 0)
                        ((bf16_t*)Yv)[(size_t)row * D_MODEL + col] = (bf16_t)vv;
                    else
                        ((float*)Yv)[(size_t)row * D_MODEL + col] = vv;
                }
    }
}

__global__ void __launch_bounds__(256, 3)
k_gemm_qkv(const bf16_t* __restrict__ X,
           const bf16_t* __restrict__ Wq, const bf16_t* __restrict__ Wk,
           const bf16_t* __restrict__ Wv,
           bf16_t* __restrict__ Qb, bf16_t* __restrict__ Kb, bf16_t* __restrict__ Vt)
{
    __shared__ __align__(16) bf16_t smem[128 * LDT];   // 18432 B
    const int sel = blockIdx.y >> 3;           // 0=Q 1=K 2=V
    const int n0  = (blockIdx.y & 7) * 128;
    const int m0  = blockIdx.x * 128;
    if (sel == 0)      gemm128<0>(smem, X, Wq, Qb, m0, n0, QSCALE);
    else if (sel == 1) gemm128<0>(smem, X, Wk, Kb, m0, n0, 1.0f);
    else               gemm128<1>(smem, X, Wv, Vt, m0, n0, 1.0f);
}

__global__ void __launch_bounds__(256, 3)
k_gemm_out(const bf16_t* __restrict__ X, const bf16_t* __restrict__ W,
           float* __restrict__ Y)
{
    __shared__ __align__(16) bf16_t smem[128 * LDT];
    gemm128<2>(smem, X, W, Y, blockIdx.x * 128, blockIdx.y * 128, 1.0f);
}

// ---------------------------------------------------------------------------
// Attention, Q-tile 128. 4 waves in a 2x2 split: wq = q-strip of 64 rows,
// wk = kv-half of 32 rows per 64-kv tile. Per wave-iter: 4 K-frag + 4 V-frag
// ds_read_b128 (was 16) -- K/V LDS duplication across waves halved, the DS
// pipe was the critical pipe (round-1 post-mortem). Partner h-exchange for
// the PV A-frags via v_permlane32_swap_b32 (VALU) instead of __shfl_xor (DS).
// Row-sum via ones-column MFMA (acc_s layout == acc_o layout). Epilogue: wk=1
// waves blob acc_o+acc_s into LDS, wk=0 adds and stores (once per kernel).
// Double-buffered K/V, stage t+1 issued before compute of t, single fused
// vmcnt(0) lgkmcnt(0) + barrier per tile. Ob may alias Qb (Q read up-front;
// block-disjoint slices).
// ---------------------------------------------------------------------------
__global__ void __launch_bounds__(256, 2)
k_attn(const bf16_t* __restrict__ Qb, const bf16_t* __restrict__ Kb,
       const bf16_t* __restrict__ Vt, bf16_t* __restrict__ Ob)
{
    // arena: main loop lK[2][4096]+lV[2][4096] bf16 (32 KiB);
    // epilogue reuses it as 2 x 64 blobs of 96 floats (stride 100 -> 50 KiB).
    __shared__ __align__(16) char arena[51200];
    bf16_t* lK = (bf16_t*)arena;               // [2][64*64] swizzled chunks
    bf16_t* lV = (bf16_t*)(arena + 16384);     // [2][64*64] swizzled chunks

    const int tid  = threadIdx.x;
    const int lane = tid & 63;
    const int w    = tid >> 6;
    const int wq   = w >> 1;      // q-strip (64 rows)
    const int wk   = w & 1;       // kv-half (32 rows)
    const int l31  = lane & 31;
    const int h    = lane >> 5;

    const int bh = blockIdx.x;    // 0..31
    const int b_ = bh >> 4, hh = bh & 15;
    const int q0 = blockIdx.y * 128;

    const size_t base = (size_t)b_ * SEQ * D_MODEL + (size_t)hh * DHEAD;
    const bf16_t* Qp = Qb + base;
    const bf16_t* Kp = Kb + base;
    const bf16_t* Vp = Vt + (size_t)bh * DHEAD * SEQ;   // [dh][s]

    // Q B-frags in regs: B[n = q = l31][k = dh-local h*8+j], chunk c = dh/16
    bf16x8 qf[2][4];
#pragma unroll
    for (int qh = 0; qh < 2; ++qh) {
        const int qrow = q0 + wq * 64 + qh * 32 + l31;
#pragma unroll
        for (int c = 0; c < 4; ++c)
            qf[qh][c] = *(const bf16x8*)&Qp[(size_t)qrow * D_MODEL + c * 16 + h * 8];
    }

    // staging: 512 chunks per tile, 2 per thread; chunk c -> row c>>3, slot
    // c&7, global chunk g = (c&7) ^ (row&7). Note (r0+32)&7 == r0&7.
    const int c0 = tid, c1 = tid + 256;
    const int r0 = c0 >> 3, g0 = (c0 & 7) ^ (r0 & 7);
    const int r1 = r0 + 32;
    const bf16_t* gK0 = Kp + (size_t)r0 * D_MODEL + g0 * 8;
    const bf16_t* gK1 = Kp + (size_t)r1 * D_MODEL + g0 * 8;
    const bf16_t* gV0 = Vp + (size_t)r0 * SEQ + g0 * 8;
    const bf16_t* gV1 = Vp + (size_t)r1 * SEQ + g0 * 8;

    // fragment read offsets (row-dependent XOR slot)
    int koff[4], voff[2][2];
#pragma unroll
    for (int c = 0; c < 4; ++c) {
        const int row = wk * 32 + l31;               // kv row (wave's half)
        koff[c] = row * 64 + (((2 * c + h) ^ (row & 7)) * 8);
    }
#pragma unroll
    for (int a = 0; a < 2; ++a)
#pragma unroll
        for (int ck = 0; ck < 2; ++ck) {
            const int row = a * 32 + l31;            // dh row
            const int ch  = 4 * wk + 2 * ck + h;     // kv chunk within row
            voff[a][ck] = row * 64 + ((ch ^ (row & 7)) * 8);
        }

    bf16x8 onef;
#pragma unroll
    for (int i = 0; i < 8; ++i) onef[i] = (bf16_t)1.0f;

    f32x16 acc_o[2][2];            // [qh][a]  D[m=q][n=dh]
    f32x16 acc_s[2];               // [qh]     rowsum (ones-column PV)
#pragma unroll
    for (int qh = 0; qh < 2; ++qh) {
#pragma unroll
        for (int i = 0; i < 16; ++i) {
            acc_o[qh][0][i] = 0.f; acc_o[qh][1][i] = 0.f; acc_s[qh][i] = 0.f;
        }
    }

    // ---- prologue: stage tile 0 into buf 0, drain, barrier
    async_ld16(gK0, &lK[c0 * 8]);
    async_ld16(gK1, &lK[c1 * 8]);
    async_ld16(gV0, &lV[c0 * 8]);
    async_ld16(gV1, &lV[c1 * 8]);
    asm volatile("s_waitcnt vmcnt(0)\n\ts_barrier" ::: "memory");

    int cur = 0;
    const int NT = SEQ / 64;       // 32
    for (int t = 0; t < NT; ++t) {
        // ---- issue next-tile DMA first; latency hides under this tile's math
        if (t + 1 < NT) {
            const int kv0 = (t + 1) * 64;
            const int nb = (cur ^ 1) * 4096;
            async_ld16(gK0 + (size_t)kv0 * D_MODEL, &lK[nb + c0 * 8]);
            async_ld16(gK1 + (size_t)kv0 * D_MODEL, &lK[nb + c1 * 8]);
            async_ld16(gV0 + kv0, &lV[nb + c0 * 8]);
            async_ld16(gV1 + kv0, &lV[nb + c1 * 8]);
        }
        const bf16_t* lKc = lK + cur * 4096;
        const bf16_t* lVc = lV + cur * 4096;

        // ---- S^T: D[m = kv-local(32)][n = q(32)], shared kf across both qh
        bf16x8 kf[4];
#pragma unroll
        for (int c = 0; c < 4; ++c) kf[c] = *(const bf16x8*)&lKc[koff[c]];

        f32x16 st[2];
#pragma unroll
        for (int qh = 0; qh < 2; ++qh)
#pragma unroll
            for (int i = 0; i < 16; ++i) st[qh][i] = 0.f;
        __builtin_amdgcn_s_setprio(1);
#pragma unroll
        for (int qh = 0; qh < 2; ++qh)
#pragma unroll
            for (int c = 0; c < 4; ++c)
                st[qh] = __builtin_amdgcn_mfma_f32_32x32x16_bf16(
                    kf[c], qf[qh][c], st[qh], 0, 0, 0);
        __builtin_amdgcn_s_setprio(0);

        // ---- exp2 + pack: pk[qh][g][r] = P[kv-local = 8g+4h+r][q = l31]
        bf16x4 pk[2][4];
#pragma unroll
        for (int qh = 0; qh < 2; ++qh)
#pragma unroll
            for (int g = 0; g < 4; ++g)
#pragma unroll
                for (int r = 0; r < 4; ++r)
                    pk[qh][g][r] = (bf16_t)__builtin_amdgcn_exp2f(st[qh][g * 4 + r]);

        // ---- assemble PV A-frags via permlane32_swap:
        // pf[qh][ck] = A[m = q = l31][k = kv-local 16ck + 8h + j]
        // dwords: {swap(pk[2ck].d0, pk[2ck+1].d0), swap(.d1, .d1)} -> lo=a, hi=b
        bf16x8 pf[2][2];
#pragma unroll
        for (int qh = 0; qh < 2; ++qh)
#pragma unroll
            for (int ck = 0; ck < 2; ++ck) {
                union { bf16x4 v; uint32_t d[2]; } ua, ub;
                ua.v = pk[qh][2 * ck];
                ub.v = pk[qh][2 * ck + 1];
                uint32_t a0 = ua.d[0], b0 = ub.d[0];
                uint32_t a1 = ua.d[1], b1 = ub.d[1];
                plswap(a0, b0);
                plswap(a1, b1);
                union { bf16x8 v; uint32_t d[4]; } up;
                up.d[0] = a0; up.d[1] = a1; up.d[2] = b0; up.d[3] = b1;
                pf[qh][ck] = up.v;
            }

        // ---- PV + ones-column row-sum
        __builtin_amdgcn_s_setprio(1);
#pragma unroll
        for (int qh = 0; qh < 2; ++qh)
#pragma unroll
            for (int ck = 0; ck < 2; ++ck)
                acc_s[qh] = __builtin_amdgcn_mfma_f32_32x32x16_bf16(
                    pf[qh][ck], onef, acc_s[qh], 0, 0, 0);
#pragma unroll
        for (int a = 0; a < 2; ++a)
#pragma unroll
            for (int ck = 0; ck < 2; ++ck) {
                bf16x8 vf = *(const bf16x8*)&lVc[voff[a][ck]];
#pragma unroll
                for (int qh = 0; qh < 2; ++qh)
                    acc_o[qh][a] = __builtin_amdgcn_mfma_f32_32x32x16_bf16(
                        pf[qh][ck], vf, acc_o[qh][a], 0, 0, 0);
            }
        __builtin_amdgcn_s_setprio(0);

        // ---- own DMA + LDS ops drained, then block rendezvous (one asm so
        // nothing is scheduled between the waits and the barrier).
        asm volatile("s_waitcnt vmcnt(0) lgkmcnt(0)\n\ts_barrier" ::: "memory");
        cur ^= 1;
    }

    // ---- epilogue: combine wk pairs through LDS (arena reused; loop's final
    // barrier guarantees all tile reads are done).
    union F16 { f32x16 v; f32x4 q[4]; };
    float* blob = (float*)arena + ((size_t)(wq * 64 + lane)) * 100;  // 400B stride

    if (wk) {
#pragma unroll
        for (int qh = 0; qh < 2; ++qh) {
#pragma unroll
            for (int a = 0; a < 2; ++a) {
                F16 u; u.v = acc_o[qh][a];
#pragma unroll
                for (int i = 0; i < 4; ++i)
                    *(f32x4*)&blob[(qh * 8 + a * 4 + i) * 4] = u.q[i];
            }
            F16 s; s.v = acc_s[qh];
#pragma unroll
            for (int i = 0; i < 4; ++i)
                *(f32x4*)&blob[64 + (qh * 4 + i) * 4] = s.q[i];
        }
    }
    __syncthreads();
    if (!wk) {
#pragma unroll
        for (int qh = 0; qh < 2; ++qh) {
#pragma unroll
            for (int a = 0; a < 2; ++a) {
                F16 u; u.v = acc_o[qh][a];
#pragma unroll
                for (int i = 0; i < 4; ++i)
                    u.q[i] += *(const f32x4*)&blob[(qh * 8 + a * 4 + i) * 4];
                acc_o[qh][a] = u.v;
            }
            F16 s; s.v = acc_s[qh];
#pragma unroll
            for (int i = 0; i < 4; ++i)
                s.q[i] += *(const f32x4*)&blob[64 + (qh * 4 + i) * 4];
            acc_s[qh] = s.v;
        }

        // O / rowsum; 32x32 C-layout row = r + 8g + 4h, col = l31
#pragma unroll
        for (int qh = 0; qh < 2; ++qh)
#pragma unroll
            for (int g = 0; g < 4; ++g)
#pragma unroll
                for (int r = 0; r < 4; ++r) {
                    const float inv = 1.0f / acc_s[qh][g * 4 + r];
                    const int row = b_ * SEQ + q0 + wq * 64 + qh * 32 + (r + 8 * g + 4 * h);
                    const size_t rb = (size_t)row * D_MODEL + hh * DHEAD + l31;
                    Ob[rb]      = (bf16_t)(acc_o[qh][0][g * 4 + r] * inv);
                    Ob[rb + 32] = (bf16_t)(acc_o[qh][1][g * 4 + r] * inv);
                }
    }
}

// ---------------------------------------------------------------------------
extern "C" void kernel_launch(void* const* d_in, const int* in_sizes, int n_in,
                              void* d_out, int out_size, void* d_ws, size_t ws_size,
                              hipStream_t stream)
{
    const float* x  = (const float*)d_in[0];
    const float* Wq = (const float*)d_in[1];
    const float* Wk = (const float*)d_in[2];
    const float* Wv = (const float*)d_in[3];
    const float* Wo = (const float*)d_in[4];
    float* out = (float*)d_out;

    const size_t wmat = (size_t)D_MODEL * D_MODEL;  // 1M elements
    const size_t mat  = (size_t)NROWS * D_MODEL;    // 4M elements
    bf16_t* Wqb = (bf16_t*)d_ws;
    bf16_t* Wkb = Wqb + wmat;
    bf16_t* Wvb = Wkb + wmat;
    bf16_t* Wob = Wvb + wmat;
    bf16_t* Xb  = Wob + wmat;
    bf16_t* Qb  = Xb + mat;
    bf16_t* Kb  = Qb + mat;
    bf16_t* Vt  = Kb + mat;                          // [bh][dh][s]
    bf16_t* Ab  = Qb;                                // alias (see k_attn)

    dim3 blk(256);
    k_cvt<<<dim3(4096), blk, 0, stream>>>(Wq, Wk, Wv, Wo, x, Wqb, Wkb, Wvb, Wob, Xb);
    k_gemm_qkv<<<dim3(32, 24), blk, 0, stream>>>(Xb, Wqb, Wkb, Wvb, Qb, Kb, Vt);
    k_attn<<<dim3(32, 16), blk, 0, stream>>>(Qb, Kb, Vt, Ab);
    k_gemm_out<<<dim3(32, 8), blk, 0, stream>>>(Ab, Wob, out);
}

// Round 3
// 179.018 us; speedup vs baseline: 1.0162x; 1.0002x over previous
//
#include <hip/hip_runtime.h>
#include <stdint.h>

typedef __bf16 bf16_t;
typedef __bf16 bf16x4 __attribute__((ext_vector_type(4)));
typedef __bf16 bf16x8 __attribute__((ext_vector_type(8)));
typedef float  f32x4  __attribute__((ext_vector_type(4)));
typedef float  f32x16 __attribute__((ext_vector_type(16)));

#define D_MODEL 1024
#define SEQ     2048
#define BATCH   2
#define NHEAD   16
#define DHEAD   64
#define NROWS   (BATCH*SEQ)   // 4096
#define LDT     72            // GEMM V-transpose buffer stride (16B-aligned)

// log2(e): folded into Q scale so attn uses v_exp_f32 (exp2) directly.
#define QSCALE  (0.125f * 1.4426950408889634f)

// async 16B global->LDS DMA (m97). LDS dest must be wave-uniform base + lane*16.
__device__ __forceinline__ void async_ld16(const bf16_t* g, bf16_t* l) {
    __builtin_amdgcn_global_load_lds(
        (const __attribute__((address_space(1))) uint32_t*)(uintptr_t)g,
        (__attribute__((address_space(3))) uint32_t*)(uintptr_t)l,
        16, 0, 0);
}

__device__ __forceinline__ bf16x8 cvt8(f32x4 lo, f32x4 hi) {
    bf16x8 o;
#pragma unroll
    for (int i = 0; i < 4; ++i) { o[i] = (bf16_t)lo[i]; o[4 + i] = (bf16_t)hi[i]; }
    return o;
}

// v_permlane32_swap_b32 a, b:  a' = {a[0:31], b[0:31]},  b' = {a[32:63], b[32:63]}
__device__ __forceinline__ void plswap(uint32_t& a, uint32_t& b) {
    asm("v_permlane32_swap_b32 %0, %1" : "+v"(a), "+v"(b));
}

// ---------------------------------------------------------------------------
// f32 -> bf16 pre-convert of Wq,Wk,Wv,Wo (512 blocks each) + x (2048 blocks).
// ---------------------------------------------------------------------------
__global__ void __launch_bounds__(256)
k_cvt(const float* __restrict__ w0, const float* __restrict__ w1,
      const float* __restrict__ w2, const float* __restrict__ w3,
      const float* __restrict__ x,
      bf16_t* __restrict__ o0, bf16_t* __restrict__ o1,
      bf16_t* __restrict__ o2, bf16_t* __restrict__ o3,
      bf16_t* __restrict__ ox)
{
    const int blk = blockIdx.x;
    const float* s; bf16_t* d; int bi;
    if (blk < 2048) { s = x; d = ox; bi = blk; }
    else {
        const int t = blk - 2048, sel = t >> 9; bi = t & 511;
        s = (sel == 0) ? w0 : (sel == 1) ? w1 : (sel == 2) ? w2 : w3;
        d = (sel == 0) ? o0 : (sel == 1) ? o1 : (sel == 2) ? o2 : o3;
    }
    const size_t i = ((size_t)bi * 256 + threadIdx.x) * 8;
    *(bf16x8*)(d + i) = cvt8(*(const f32x4*)(s + i), *(const f32x4*)(s + i + 4));
}

// ---------------------------------------------------------------------------
// 128x128 GEMM tile: Y = X @ W^T * oscale. A and B bf16. (round-8 structure)
// Staging: global_load_lds width=16, 32-elem LDS rows, XOR-4 chunk swizzle.
// OUT_MODE: 0 = bf16 row-major; 1 = bf16 V^T [bh][dh][s]; 2 = f32 row-major.
// ---------------------------------------------------------------------------
template <int OUT_MODE>
__device__ __forceinline__ void gemm128(bf16_t* __restrict__ smem,
                                        const bf16_t* __restrict__ X,
                                        const bf16_t* __restrict__ W,
                                        void* __restrict__ Yv,
                                        int m0, int n0, float oscale)
{
    bf16_t* lA = smem;                 // 128 x 32
    bf16_t* lB = smem + 128 * 32;      // 128 x 32

    const int tid  = threadIdx.x;
    const int lane = tid & 63;
    const int w    = tid >> 6;
    const int l15  = lane & 15;
    const int quad = lane >> 4;

    const int c0 = tid, c1 = tid + 256;
    const int r0 = c0 >> 2, r1 = c1 >> 2;
    const int kc0 = (c0 & 3) ^ ((r0 >> 1) & 3);
    const int kc1 = (c1 & 3) ^ ((r1 >> 1) & 3);
    const bf16_t* gA0 = X + (size_t)(m0 + r0) * D_MODEL + kc0 * 8;
    const bf16_t* gA1 = X + (size_t)(m0 + r1) * D_MODEL + kc1 * 8;
    const bf16_t* gB0 = W + (size_t)(n0 + r0) * D_MODEL + kc0 * 8;
    const bf16_t* gB1 = W + (size_t)(n0 + r1) * D_MODEL + kc1 * 8;

    int am[4], bn[4];
    const int mw = (w >> 1) * 64, nw = (w & 1) * 64;
#pragma unroll
    for (int i = 0; i < 4; ++i) {
        const int ra = mw + i * 16 + l15;
        am[i] = ra * 32 + (quad ^ ((ra >> 1) & 3)) * 8;
        const int rb = nw + i * 16 + l15;
        bn[i] = rb * 32 + (quad ^ ((rb >> 1) & 3)) * 8;
    }

    f32x4 acc[4][4];
#pragma unroll
    for (int i = 0; i < 4; ++i)
#pragma unroll
        for (int j = 0; j < 4; ++j) acc[i][j] = f32x4{0.f, 0.f, 0.f, 0.f};

    for (int k0 = 0; k0 < D_MODEL; k0 += 32) {
        __syncthreads();
        async_ld16(gA0 + k0, &lA[c0 * 8]);
        async_ld16(gA1 + k0, &lA[c1 * 8]);
        async_ld16(gB0 + k0, &lB[c0 * 8]);
        async_ld16(gB1 + k0, &lB[c1 * 8]);
        __syncthreads();

        bf16x8 af[4], bfr[4];
#pragma unroll
        for (int i = 0; i < 4; ++i) af[i]  = *(const bf16x8*)&lA[am[i]];
#pragma unroll
        for (int i = 0; i < 4; ++i) bfr[i] = *(const bf16x8*)&lB[bn[i]];
#pragma unroll
        for (int mi = 0; mi < 4; ++mi)
#pragma unroll
            for (int ni = 0; ni < 4; ++ni)
                acc[mi][ni] = __builtin_amdgcn_mfma_f32_16x16x32_bf16(
                    af[mi], bfr[ni], acc[mi][ni], 0, 0, 0);
    }

    if constexpr (OUT_MODE == 1) {
        bf16_t* lT = smem;                        // 128 cols x LDT
#pragma unroll
        for (int h0 = 0; h0 < 2; ++h0) {
            __syncthreads();
            if ((w >> 1) == h0) {
#pragma unroll
                for (int mi = 0; mi < 4; ++mi)
#pragma unroll
                    for (int ni = 0; ni < 4; ++ni) {
                        bf16x4 pk;
#pragma unroll
                        for (int r = 0; r < 4; ++r)
                            pk[r] = (bf16_t)(acc[mi][ni][r] * oscale);
                        const int col = nw + ni * 16 + l15;
                        *(bf16x4*)&lT[col * LDT + mi * 16 + quad * 4] = pk;
                    }
            }
            __syncthreads();
            const int col = tid & 127;
            const int seg = tid >> 7;
            const int brow = m0 + h0 * 64;
            const int b = brow >> 11, sb = brow & 2047;
            const int cg = n0 + col;              // h*64+dh
            bf16_t* dst = (bf16_t*)Yv +
                ((size_t)((b << 4) | (cg >> 6)) * 64 + (cg & 63)) * SEQ + sb;
#pragma unroll
            for (int u = 0; u < 4; ++u)
                *(bf16x8*)(dst + seg * 32 + u * 8) =
                    *(const bf16x8*)&lT[col * LDT + seg * 32 + u * 8];
        }
    } else {
        // C/D layout col = lane&15, row = quad*4 + reg (m89-verified)
#pragma unroll
        for (int mi = 0; mi < 4; ++mi)
#pragma unroll
            for (int ni = 0; ni < 4; ++ni)
#pragma unroll
                for (int r = 0; r < 4; ++r) {
                    const int row = m0 + mw + mi * 16 + quad * 4 + r;
                    const int col = n0 + nw + ni * 16 + l15;
                    const float vv = acc[mi][ni][r] * oscale;
                    if constexpr (OUT_MODE == 0)
                        ((bf16_t*)Yv)[(size_t)row * D_MODEL + col] = (bf16_t)vv;
                    else
                        ((float*)Yv)[(size_t)row * D_MODEL + col] = vv;
                }
    }
}

__global__ void __launch_bounds__(256, 3)
k_gemm_qkv(const bf16_t* __restrict__ X,
           const bf16_t* __restrict__ Wq, const bf16_t* __restrict__ Wk,
           const bf16_t* __restrict__ Wv,
           bf16_t* __restrict__ Qb, bf16_t* __restrict__ Kb, bf16_t* __restrict__ Vt)
{
    __shared__ __align__(16) bf16_t smem[128 * LDT];   // 18432 B
    // desync co-resident triplets (768 blocks = 3/CU; triplet split by y>>3):
    // identical instruction streams phase-lock on the MFMA/VALU pipes (r2
    // post-mortem: pipe-busy percentages sum to ~wall). One-time stagger.
    const int ph = blockIdx.y >> 3;
    if (ph == 1)      __builtin_amdgcn_s_sleep(15);   // ~960 cyc
    else if (ph == 2) __builtin_amdgcn_s_sleep(30);   // ~1920 cyc
    const int sel = blockIdx.y >> 3;           // 0=Q 1=K 2=V
    const int n0  = (blockIdx.y & 7) * 128;
    const int m0  = blockIdx.x * 128;
    if (sel == 0)      gemm128<0>(smem, X, Wq, Qb, m0, n0, QSCALE);
    else if (sel == 1) gemm128<0>(smem, X, Wk, Kb, m0, n0, 1.0f);
    else               gemm128<1>(smem, X, Wv, Vt, m0, n0, 1.0f);
}

__global__ void __launch_bounds__(256, 3)
k_gemm_out(const bf16_t* __restrict__ X, const bf16_t* __restrict__ W,
           float* __restrict__ Y)
{
    __shared__ __align__(16) bf16_t smem[128 * LDT];
    gemm128<2>(smem, X, W, Y, blockIdx.x * 128, blockIdx.y * 128, 1.0f);
}

// ---------------------------------------------------------------------------
// Attention, Q-tile 128. 4 waves in a 2x2 split: wq = q-strip of 64 rows,
// wk = kv-half of 32 rows per 64-kv tile. Per wave-iter: 4 K-frag + 4 V-frag
// ds_read_b128. Partner h-exchange via v_permlane32_swap_b32 (VALU pipe).
// Row-sum via ones-column MFMA. Double-buffered K/V, stage t+1 before compute
// of t, single fused vmcnt/lgkmcnt + barrier per tile.
// Round-3 change: one-time s_sleep stagger for the second co-resident block
// (pairs are (id, id+256) -> split on blockIdx.y>=8). r2 post-mortem showed
// MfmaUtil+VALUBusy+DS ~= 100% of wall: the two blocks per CU run identical
// streams in phase-lock, so the matrix/vector/LDS pipes never overlap.
// Anti-phasing them lets block A's exp2/VALU run under block B's MFMA.
// Ob may alias Qb (Q read up-front; block-disjoint slices).
// ---------------------------------------------------------------------------
__global__ void __launch_bounds__(256, 2)
k_attn(const bf16_t* __restrict__ Qb, const bf16_t* __restrict__ Kb,
       const bf16_t* __restrict__ Vt, bf16_t* __restrict__ Ob)
{
    // arena: main loop lK[2][4096]+lV[2][4096] bf16 (32 KiB);
    // epilogue reuses it as 2 x 64 blobs of 96 floats (stride 100 -> 50 KiB).
    __shared__ __align__(16) char arena[51200];
    bf16_t* lK = (bf16_t*)arena;               // [2][64*64] swizzled chunks
    bf16_t* lV = (bf16_t*)(arena + 16384);     // [2][64*64] swizzled chunks

    // desync co-resident block pairs (512 blocks = 2/CU, pair = (id,id+256))
    if (blockIdx.y >= 8) __builtin_amdgcn_s_sleep(13);   // ~832 cyc ~ half iter

    const int tid  = threadIdx.x;
    const int lane = tid & 63;
    const int w    = tid >> 6;
    const int wq   = w >> 1;      // q-strip (64 rows)
    const int wk   = w & 1;       // kv-half (32 rows)
    const int l31  = lane & 31;
    const int h    = lane >> 5;

    const int bh = blockIdx.x;    // 0..31
    const int b_ = bh >> 4, hh = bh & 15;
    const int q0 = blockIdx.y * 128;

    const size_t base = (size_t)b_ * SEQ * D_MODEL + (size_t)hh * DHEAD;
    const bf16_t* Qp = Qb + base;
    const bf16_t* Kp = Kb + base;
    const bf16_t* Vp = Vt + (size_t)bh * DHEAD * SEQ;   // [dh][s]

    // Q B-frags in regs: B[n = q = l31][k = dh-local h*8+j], chunk c = dh/16
    bf16x8 qf[2][4];
#pragma unroll
    for (int qh = 0; qh < 2; ++qh) {
        const int qrow = q0 + wq * 64 + qh * 32 + l31;
#pragma unroll
        for (int c = 0; c < 4; ++c)
            qf[qh][c] = *(const bf16x8*)&Qp[(size_t)qrow * D_MODEL + c * 16 + h * 8];
    }

    // staging: 512 chunks per tile, 2 per thread; chunk c -> row c>>3, slot
    // c&7, global chunk g = (c&7) ^ (row&7). Note (r0+32)&7 == r0&7.
    const int c0 = tid, c1 = tid + 256;
    const int r0 = c0 >> 3, g0 = (c0 & 7) ^ (r0 & 7);
    const int r1 = r0 + 32;
    const bf16_t* gK0 = Kp + (size_t)r0 * D_MODEL + g0 * 8;
    const bf16_t* gK1 = Kp + (size_t)r1 * D_MODEL + g0 * 8;
    const bf16_t* gV0 = Vp + (size_t)r0 * SEQ + g0 * 8;
    const bf16_t* gV1 = Vp + (size_t)r1 * SEQ + g0 * 8;

    // fragment read offsets (row-dependent XOR slot)
    int koff[4], voff[2][2];
#pragma unroll
    for (int c = 0; c < 4; ++c) {
        const int row = wk * 32 + l31;               // kv row (wave's half)
        koff[c] = row * 64 + (((2 * c + h) ^ (row & 7)) * 8);
    }
#pragma unroll
    for (int a = 0; a < 2; ++a)
#pragma unroll
        for (int ck = 0; ck < 2; ++ck) {
            const int row = a * 32 + l31;            // dh row
            const int ch  = 4 * wk + 2 * ck + h;     // kv chunk within row
            voff[a][ck] = row * 64 + ((ch ^ (row & 7)) * 8);
        }

    bf16x8 onef;
#pragma unroll
    for (int i = 0; i < 8; ++i) onef[i] = (bf16_t)1.0f;

    f32x16 acc_o[2][2];            // [qh][a]  D[m=q][n=dh]
    f32x16 acc_s[2];               // [qh]     rowsum (ones-column PV)
#pragma unroll
    for (int qh = 0; qh < 2; ++qh) {
#pragma unroll
        for (int i = 0; i < 16; ++i) {
            acc_o[qh][0][i] = 0.f; acc_o[qh][1][i] = 0.f; acc_s[qh][i] = 0.f;
        }
    }

    // ---- prologue: stage tile 0 into buf 0, drain, barrier
    async_ld16(gK0, &lK[c0 * 8]);
    async_ld16(gK1, &lK[c1 * 8]);
    async_ld16(gV0, &lV[c0 * 8]);
    async_ld16(gV1, &lV[c1 * 8]);
    asm volatile("s_waitcnt vmcnt(0)\n\ts_barrier" ::: "memory");

    int cur = 0;
    const int NT = SEQ / 64;       // 32
    for (int t = 0; t < NT; ++t) {
        // ---- issue next-tile DMA first; latency hides under this tile's math
        if (t + 1 < NT) {
            const int kv0 = (t + 1) * 64;
            const int nb = (cur ^ 1) * 4096;
            async_ld16(gK0 + (size_t)kv0 * D_MODEL, &lK[nb + c0 * 8]);
            async_ld16(gK1 + (size_t)kv0 * D_MODEL, &lK[nb + c1 * 8]);
            async_ld16(gV0 + kv0, &lV[nb + c0 * 8]);
            async_ld16(gV1 + kv0, &lV[nb + c1 * 8]);
        }
        const bf16_t* lKc = lK + cur * 4096;
        const bf16_t* lVc = lV + cur * 4096;

        // ---- S^T: D[m = kv-local(32)][n = q(32)], shared kf across both qh
        bf16x8 kf[4];
#pragma unroll
        for (int c = 0; c < 4; ++c) kf[c] = *(const bf16x8*)&lKc[koff[c]];

        f32x16 st[2];
#pragma unroll
        for (int qh = 0; qh < 2; ++qh)
#pragma unroll
            for (int i = 0; i < 16; ++i) st[qh][i] = 0.f;
        __builtin_amdgcn_s_setprio(1);
#pragma unroll
        for (int qh = 0; qh < 2; ++qh)
#pragma unroll
            for (int c = 0; c < 4; ++c)
                st[qh] = __builtin_amdgcn_mfma_f32_32x32x16_bf16(
                    kf[c], qf[qh][c], st[qh], 0, 0, 0);
        __builtin_amdgcn_s_setprio(0);

        // ---- exp2 + pack: pk[qh][g][r] = P[kv-local = 8g+4h+r][q = l31]
        bf16x4 pk[2][4];
#pragma unroll
        for (int qh = 0; qh < 2; ++qh)
#pragma unroll
            for (int g = 0; g < 4; ++g)
#pragma unroll
                for (int r = 0; r < 4; ++r)
                    pk[qh][g][r] = (bf16_t)__builtin_amdgcn_exp2f(st[qh][g * 4 + r]);

        // ---- assemble PV A-frags via permlane32_swap:
        // pf[qh][ck] = A[m = q = l31][k = kv-local 16ck + 8h + j]
        bf16x8 pf[2][2];
#pragma unroll
        for (int qh = 0; qh < 2; ++qh)
#pragma unroll
            for (int ck = 0; ck < 2; ++ck) {
                union { bf16x4 v; uint32_t d[2]; } ua, ub;
                ua.v = pk[qh][2 * ck];
                ub.v = pk[qh][2 * ck + 1];
                uint32_t a0 = ua.d[0], b0 = ub.d[0];
                uint32_t a1 = ua.d[1], b1 = ub.d[1];
                plswap(a0, b0);
                plswap(a1, b1);
                union { bf16x8 v; uint32_t d[4]; } up;
                up.d[0] = a0; up.d[1] = a1; up.d[2] = b0; up.d[3] = b1;
                pf[qh][ck] = up.v;
            }

        // ---- PV + ones-column row-sum
        __builtin_amdgcn_s_setprio(1);
#pragma unroll
        for (int qh = 0; qh < 2; ++qh)
#pragma unroll
            for (int ck = 0; ck < 2; ++ck)
                acc_s[qh] = __builtin_amdgcn_mfma_f32_32x32x16_bf16(
                    pf[qh][ck], onef, acc_s[qh], 0, 0, 0);
#pragma unroll
        for (int a = 0; a < 2; ++a)
#pragma unroll
            for (int ck = 0; ck < 2; ++ck) {
                bf16x8 vf = *(const bf16x8*)&lVc[voff[a][ck]];
#pragma unroll
                for (int qh = 0; qh < 2; ++qh)
                    acc_o[qh][a] = __builtin_amdgcn_mfma_f32_32x32x16_bf16(
                        pf[qh][ck], vf, acc_o[qh][a], 0, 0, 0);
            }
        __builtin_amdgcn_s_setprio(0);

        // ---- own DMA + LDS ops drained, then block rendezvous (one asm so
        // nothing is scheduled between the waits and the barrier).
        asm volatile("s_waitcnt vmcnt(0) lgkmcnt(0)\n\ts_barrier" ::: "memory");
        cur ^= 1;
    }

    // ---- epilogue: combine wk pairs through LDS (arena reused; loop's final
    // barrier guarantees all tile reads are done).
    union F16 { f32x16 v; f32x4 q[4]; };
    float* blob = (float*)arena + ((size_t)(wq * 64 + lane)) * 100;  // 400B stride

    if (wk) {
#pragma unroll
        for (int qh = 0; qh < 2; ++qh) {
#pragma unroll
            for (int a = 0; a < 2; ++a) {
                F16 u; u.v = acc_o[qh][a];
#pragma unroll
                for (int i = 0; i < 4; ++i)
                    *(f32x4*)&blob[(qh * 8 + a * 4 + i) * 4] = u.q[i];
            }
            F16 s; s.v = acc_s[qh];
#pragma unroll
            for (int i = 0; i < 4; ++i)
                *(f32x4*)&blob[64 + (qh * 4 + i) * 4] = s.q[i];
        }
    }
    __syncthreads();
    if (!wk) {
#pragma unroll
        for (int qh = 0; qh < 2; ++qh) {
#pragma unroll
            for (int a = 0; a < 2; ++a) {
                F16 u; u.v = acc_o[qh][a];
#pragma unroll
                for (int i = 0; i < 4; ++i)
                    u.q[i] += *(const f32x4*)&blob[(qh * 8 + a * 4 + i) * 4];
                acc_o[qh][a] = u.v;
            }
            F16 s; s.v = acc_s[qh];
#pragma unroll
            for (int i = 0; i < 4; ++i)
                s.q[i] += *(const f32x4*)&blob[64 + (qh * 4 + i) * 4];
            acc_s[qh] = s.v;
        }

        // O / rowsum; 32x32 C-layout row = r + 8g + 4h, col = l31
#pragma unroll
        for (int qh = 0; qh < 2; ++qh)
#pragma unroll
            for (int g = 0; g < 4; ++g)
#pragma unroll
                for (int r = 0; r < 4; ++r) {
                    const float inv = 1.0f / acc_s[qh][g * 4 + r];
                    const int row = b_ * SEQ + q0 + wq * 64 + qh * 32 + (r + 8 * g + 4 * h);
                    const size_t rb = (size_t)row * D_MODEL + hh * DHEAD + l31;
                    Ob[rb]      = (bf16_t)(acc_o[qh][0][g * 4 + r] * inv);
                    Ob[rb + 32] = (bf16_t)(acc_o[qh][1][g * 4 + r] * inv);
                }
    }
}

// ---------------------------------------------------------------------------
extern "C" void kernel_launch(void* const* d_in, const int* in_sizes, int n_in,
                              void* d_out, int out_size, void* d_ws, size_t ws_size,
                              hipStream_t stream)
{
    const float* x  = (const float*)d_in[0];
    const float* Wq = (const float*)d_in[1];
    const float* Wk = (const float*)d_in[2];
    const float* Wv = (const float*)d_in[3];
    const float* Wo = (const float*)d_in[4];
    float* out = (float*)d_out;

    const size_t wmat = (size_t)D_MODEL * D_MODEL;  // 1M elements
    const size_t mat  = (size_t)NROWS * D_MODEL;    // 4M elements
    bf16_t* Wqb = (bf16_t*)d_ws;
    bf16_t* Wkb = Wqb + wmat;
    bf16_t* Wvb = Wkb + wmat;
    bf16_t* Wob = Wvb + wmat;
    bf16_t* Xb  = Wob + wmat;
    bf16_t* Qb  = Xb + mat;
    bf16_t* Kb  = Qb + mat;
    bf16_t* Vt  = Kb + mat;                          // [bh][dh][s]
    bf16_t* Ab  = Qb;                                // alias (see k_attn)

    dim3 blk(256);
    k_cvt<<<dim3(4096), blk, 0, stream>>>(Wq, Wk, Wv, Wo, x, Wqb, Wkb, Wvb, Wob, Xb);
    k_gemm_qkv<<<dim3(32, 24), blk, 0, stream>>>(Xb, Wqb, Wkb, Wvb, Qb, Kb, Vt);
    k_attn<<<dim3(32, 16), blk, 0, stream>>>(Qb, Kb, Vt, Ab);
    k_gemm_out<<<dim3(32, 8), blk, 0, stream>>>(Ab, Wob, out);
}